// Round 1
// baseline (694.817 us; speedup 1.0000x reference)
//
#include <hip/hip_runtime.h>

#define NODE 8192
#define FEAT 64
#define BATCH 4
#define OUTD 64
#define NCOL 256  // BATCH*OUTD

typedef float f32x4 __attribute__((ext_vector_type(4)));
typedef short s16x8 __attribute__((ext_vector_type(8)));
typedef int   i32x4 __attribute__((ext_vector_type(4)));

__device__ __forceinline__ short f2bf(float f) {
    // round-to-nearest-even fp32 -> bf16 (inputs are finite; no NaN handling needed)
    unsigned u = __builtin_bit_cast(unsigned, f);
    u += 0x7FFFu + ((u >> 16) & 1u);
    return (short)(u >> 16);
}

// ---------------------------------------------------------------------------
// k0: bias2[o] = b_out[o] + sum_f nl_b[f] * w_out[o,f]
// ---------------------------------------------------------------------------
__global__ void bias2_kernel(const float* __restrict__ nl_b,
                             const float* __restrict__ w_out,
                             const float* __restrict__ b_out,
                             float* __restrict__ bias2) {
    int o = threadIdx.x;
    if (o < OUTD) {
        float s = b_out[o];
        for (int f = 0; f < FEAT; ++f) s += nl_b[f] * w_out[o * FEAT + f];
        bias2[o] = s;
    }
}

// ---------------------------------------------------------------------------
// k1: Yt[c][j] = bf16( sum_f W2[o,f] * x[b,j,f] ),  c = b*64+o
//     W2[o,f] = w_out[o,f] * (nl_w[f]/sqrt(2))
// MFMA with m=o (A=W2), n=j (B=x with f as K) -> writes Y transposed so the
// big GEMM's B-fragments are 16B-contiguous along K.
// grid: 4 b * 128 j-chunks = 512 blocks, 256 threads (4 waves; wave = o-tile)
// ---------------------------------------------------------------------------
__global__ __launch_bounds__(256) void build_yt_kernel(
    const float* __restrict__ x, const float* __restrict__ nl_w,
    const float* __restrict__ w_out, unsigned short* __restrict__ yt) {
    const int b    = blockIdx.x >> 7;
    const int j0   = (blockIdx.x & 127) << 6;
    const int lane = threadIdx.x & 63;
    const int wv   = threadIdx.x >> 6;   // 0..3 -> o-tile
    const int t16  = lane & 15;
    const int quad = lane >> 4;
    const int o0   = wv << 4;

    f32x4 acc[4];
#pragma unroll
    for (int nt = 0; nt < 4; ++nt) acc[nt] = (f32x4){0.f, 0.f, 0.f, 0.f};

#pragma unroll
    for (int ks = 0; ks < 2; ++ks) {
        const int f0 = ks * 32 + quad * 8;
        // A-frag: lane holds A[m=t16][k=quad*8+j], m=o, k=f
        const float* wp = w_out + (o0 + t16) * FEAT + f0;
        const float* sp = nl_w + f0;
        f32x4 w0 = *(const f32x4*)wp;
        f32x4 w1 = *(const f32x4*)(wp + 4);
        f32x4 s0 = *(const f32x4*)sp;
        f32x4 s1 = *(const f32x4*)(sp + 4);
        s16x8 af;
#pragma unroll
        for (int i = 0; i < 4; ++i) {
            af[i]     = f2bf(w0[i] * (0.70710678118654752f * s0[i]));
            af[i + 4] = f2bf(w1[i] * (0.70710678118654752f * s1[i]));
        }
#pragma unroll
        for (int nt = 0; nt < 4; ++nt) {
            // B-frag: lane holds B[k=f][n=j], j = j0+nt*16+t16, 8 consecutive f
            const float* xp =
                x + ((size_t)b * NODE + (j0 + nt * 16 + t16)) * FEAT + f0;
            f32x4 x0 = *(const f32x4*)xp;
            f32x4 x1 = *(const f32x4*)(xp + 4);
            s16x8 bf;
#pragma unroll
            for (int i = 0; i < 4; ++i) {
                bf[i]     = f2bf(x0[i]);
                bf[i + 4] = f2bf(x1[i]);
            }
            acc[nt] = __builtin_amdgcn_mfma_f32_16x16x32_bf16(af, bf, acc[nt], 0, 0, 0);
        }
    }
    // C/D layout: col(n=j) = lane&15, row(m=o) = quad*4 + r  [verified m89/m91]
#pragma unroll
    for (int nt = 0; nt < 4; ++nt) {
#pragma unroll
        for (int r = 0; r < 4; ++r) {
            int o = o0 + quad * 4 + r;
            int j = j0 + nt * 16 + t16;
            yt[(size_t)(b * OUTD + o) * NODE + j] = (unsigned short)f2bf(acc[nt][r]);
        }
    }
}

// ---------------------------------------------------------------------------
// k2: out[b,i,o] = sum_j adj[i,j] * Y[j, b*64+o] + bias2[o]
// 256 blocks x 512 threads (8 waves). Block = 32 rows x all 256 cols.
// wave w: m-tile = w>>2 (16 rows), n-range = (w&3)*64 (batch nq, 4 n-tiles).
// No LDS / no barriers: A fp32 direct from adj rows (cvt->bf16 in reg),
// B direct 16B loads from L2-hot Yt. Memory-bound: just stream adj.
// ---------------------------------------------------------------------------
__global__ __launch_bounds__(512, 2) void gemm_adj_kernel(
    const float* __restrict__ adj, const unsigned short* __restrict__ yt,
    const float* __restrict__ bias2, float* __restrict__ out) {
    const int lane = threadIdx.x & 63;
    const int w    = threadIdx.x >> 6;  // 0..7
    const int t16  = lane & 15;
    const int quad = lane >> 4;
    const int mh   = w >> 2;   // 0..1
    const int nq   = w & 3;    // batch index
    const int row  = blockIdx.x * 32 + mh * 16 + t16;  // A-operand row
    const int cb   = nq * 64;

    f32x4 acc[4];
#pragma unroll
    for (int nt = 0; nt < 4; ++nt) acc[nt] = (f32x4){0.f, 0.f, 0.f, 0.f};

    const float* arow = adj + (size_t)row * NODE + quad * 8;
    const unsigned short* bbase = yt + (size_t)(cb + t16) * NODE + quad * 8;

#pragma unroll 4
    for (int k = 0; k < NODE; k += 32) {
        // A-frag: A[m=t16][k' = quad*8 + j], 8 consecutive fp32 -> bf16
        f32x4 a0 = *(const f32x4*)(arow + k);
        f32x4 a1 = *(const f32x4*)(arow + k + 4);
        s16x8 af;
#pragma unroll
        for (int i = 0; i < 4; ++i) {
            af[i]     = f2bf(a0[i]);
            af[i + 4] = f2bf(a1[i]);
        }
#pragma unroll
        for (int nt = 0; nt < 4; ++nt) {
            i32x4 braw = *(const i32x4*)(bbase + (size_t)nt * 16 * NODE + k);
            s16x8 bf   = __builtin_bit_cast(s16x8, braw);
            acc[nt] = __builtin_amdgcn_mfma_f32_16x16x32_bf16(af, bf, acc[nt], 0, 0, 0);
        }
    }

    // epilogue: C/D col = t16 (n), row = quad*4 + r (m); add bias2, store fp32
    const int irow0 = blockIdx.x * 32 + mh * 16 + quad * 4;
#pragma unroll
    for (int nt = 0; nt < 4; ++nt) {
        float bv = bias2[nt * 16 + t16];
        float* op = out + ((size_t)nq * NODE + irow0) * OUTD + nt * 16 + t16;
#pragma unroll
        for (int r = 0; r < 4; ++r) {
            op[(size_t)r * OUTD] = acc[nt][r] + bv;
        }
    }
}

// ---------------------------------------------------------------------------
extern "C" void kernel_launch(void* const* d_in, const int* in_sizes, int n_in,
                              void* d_out, int out_size, void* d_ws, size_t ws_size,
                              hipStream_t stream) {
    const float* x     = (const float*)d_in[0];
    const float* adj   = (const float*)d_in[1];
    const float* nl_w  = (const float*)d_in[2];
    const float* nl_b  = (const float*)d_in[3];
    const float* w_out = (const float*)d_in[4];
    const float* b_out = (const float*)d_in[5];
    float* out = (float*)d_out;

    unsigned short* yt = (unsigned short*)d_ws;                       // 256*8192 bf16 = 4 MB
    float* bias2 = (float*)((char*)d_ws + (size_t)NCOL * NODE * 2);   // 64 fp32

    bias2_kernel<<<1, 64, 0, stream>>>(nl_b, w_out, b_out, bias2);
    build_yt_kernel<<<512, 256, 0, stream>>>(x, nl_w, w_out, yt);
    gemm_adj_kernel<<<256, 512, 0, stream>>>(adj, yt, bias2, out);
}

// Round 2
// 567.576 us; speedup vs baseline: 1.2242x; 1.2242x over previous
//
#include <hip/hip_runtime.h>

#define NODE 8192
#define FEAT 64
#define BATCH 4
#define OUTD 64
#define NCOL 256  // BATCH*OUTD

typedef float f32x4 __attribute__((ext_vector_type(4)));
typedef short s16x8 __attribute__((ext_vector_type(8)));
typedef int   i32x4 __attribute__((ext_vector_type(4)));

__device__ __forceinline__ short f2bf(float f) {
    // round-to-nearest-even fp32 -> bf16 (finite inputs)
    unsigned u = __builtin_bit_cast(unsigned, f);
    u += 0x7FFFu + ((u >> 16) & 1u);
    return (short)(u >> 16);
}

__device__ __forceinline__ s16x8 cvt8(const f32x4& lo, const f32x4& hi) {
    s16x8 r;
#pragma unroll
    for (int i = 0; i < 4; ++i) { r[i] = f2bf(lo[i]); r[i + 4] = f2bf(hi[i]); }
    return r;
}

// ---------------------------------------------------------------------------
// k0: bias2[o] = b_out[o] + sum_f nl_b[f] * w_out[o,f]
// 256 threads: 4 f-chunks x 64 o, LDS reduce.
// ---------------------------------------------------------------------------
__global__ void bias2_kernel(const float* __restrict__ nl_b,
                             const float* __restrict__ w_out,
                             const float* __restrict__ b_out,
                             float* __restrict__ bias2) {
    __shared__ float part[4][64];
    const int o = threadIdx.x & 63;
    const int fc = threadIdx.x >> 6;
    float s = 0.f;
#pragma unroll
    for (int i = 0; i < 16; ++i) {
        int f = fc * 16 + i;
        s += nl_b[f] * w_out[o * FEAT + f];
    }
    part[fc][o] = s;
    __syncthreads();
    if (fc == 0)
        bias2[o] = b_out[o] + part[0][o] + part[1][o] + part[2][o] + part[3][o];
}

// ---------------------------------------------------------------------------
// k1: Yt[b*64+o][j] = bf16( sum_f W2[o,f] * x[b,j,f] ),  W2[o,f]=w_out[o,f]*nl_w[f]/sqrt2
// Coalesced float4 staging of the 64j x 64f x-tile into padded LDS (the old
// version's 256B-strided global reads were the ~270us tail), W2 tile in LDS
// (broadcast reads). Pure VALU compute: 64 MACs per output, 16 outputs/thread.
// grid: 4 b * 128 j-chunks = 512 blocks, 256 threads.
// ---------------------------------------------------------------------------
__global__ __launch_bounds__(256) void build_yt_kernel(
    const float* __restrict__ x, const float* __restrict__ nl_w,
    const float* __restrict__ w_out, unsigned short* __restrict__ yt) {
    __shared__ float xs[64 * 65];   // [j][f], pad 65 -> bank (j+f)%32, conflict-free reads
    __shared__ float w2s[64 * 65];  // [o][f]
    const int tid = threadIdx.x;
    const int b   = (int)blockIdx.x >> 7;
    const int j0  = ((int)blockIdx.x & 127) << 6;

    // stage x tile: 16KB fully contiguous -> coalesced float4 loads
    const f32x4* src = (const f32x4*)(x + ((size_t)b * NODE + j0) * FEAT);
#pragma unroll
    for (int i = tid; i < 1024; i += 256) {
        f32x4 v = src[i];
        int j = i >> 4, f = (i & 15) << 2;
        float* d = &xs[j * 65 + f];
        d[0] = v[0]; d[1] = v[1]; d[2] = v[2]; d[3] = v[3];
    }
    // stage W2 tile (coalesced w_out reads)
    for (int i = tid; i < 4096; i += 256) {
        int f = i & 63;
        w2s[(i >> 6) * 65 + f] = w_out[i] * (0.70710678118654752f * nl_w[f]);
    }
    __syncthreads();

    const int j  = tid & 63;         // lane = j -> conflict-free xs reads
    const int o0 = (tid >> 6) << 4;  // wave-uniform o-block -> w2s reads broadcast
    float acc[16];
#pragma unroll
    for (int r = 0; r < 16; ++r) acc[r] = 0.f;
    for (int f = 0; f < 64; ++f) {
        float xv = xs[j * 65 + f];
#pragma unroll
        for (int r = 0; r < 16; ++r) acc[r] += w2s[(o0 + r) * 65 + f] * xv;
    }
#pragma unroll
    for (int r = 0; r < 16; ++r)
        yt[(size_t)(b * OUTD + o0 + r) * NODE + j0 + j] = (unsigned short)f2bf(acc[r]);
}

// ---------------------------------------------------------------------------
// k2: out[b,i,o] = sum_j adj[i,j] * Y[j, b*64+o] + bias2[o]
// Block: 512 thr = 8 waves = 2 k-halves (ks) x 4 batches (nq); block tile
// 32 rows x 256 cols; grid 256 blocks (1/CU, 8 waves/CU).
// Wave: 32r x 64c = 2 m-frags x 4 n-frags of 16x16x32 bf16 MFMA over K=4096.
// Explicit register double-buffer: 8 loads (4 A f32x4 + 4 B i32x4) for step
// k+1 issued before consuming step k -> ~8KB/wave in flight (the round-1
// kernel had VGPR=32 and serialized on every load).
// Epilogue: ks=1 waves dump acc to LDS, barrier, ks=0 waves add + bias, store.
// ---------------------------------------------------------------------------
__global__ __launch_bounds__(512, 2) void gemm_adj_kernel(
    const float* __restrict__ adj, const unsigned short* __restrict__ yt,
    const float* __restrict__ bias2, float* __restrict__ out) {
    __shared__ float red[4 * 32 * 65];  // [nq][row][col], pad 65

    const int lane = threadIdx.x & 63;
    const int w    = threadIdx.x >> 6;
    const int nq   = w & 3;
    const int ks   = w >> 2;
    const int t16  = lane & 15;
    const int quad = lane >> 4;
    const int row0 = (int)blockIdx.x << 5;
    const int kbeg = ks << 12;
    const int kend = kbeg + 4096;

    const float* a0p = adj + (size_t)(row0 + t16) * NODE + quad * 8;
    const float* a1p = a0p + (size_t)16 * NODE;
    const unsigned short* bp = yt + (size_t)(nq * 64 + t16) * NODE + quad * 8;

    f32x4 acc[2][4];
#pragma unroll
    for (int mi = 0; mi < 2; ++mi)
#pragma unroll
        for (int nt = 0; nt < 4; ++nt) acc[mi][nt] = (f32x4){0.f, 0.f, 0.f, 0.f};

    f32x4 sa[2][2], ta[2][2];
    i32x4 sb[4], tb[4];

#define GLOAD(A, B, kk)                                                      \
    {                                                                        \
        A[0][0] = *(const f32x4*)(a0p + (kk));                               \
        A[0][1] = *(const f32x4*)(a0p + (kk) + 4);                           \
        A[1][0] = *(const f32x4*)(a1p + (kk));                               \
        A[1][1] = *(const f32x4*)(a1p + (kk) + 4);                           \
        _Pragma("unroll") for (int nt = 0; nt < 4; ++nt)                     \
            B[nt] = *(const i32x4*)(bp + (size_t)nt * 16 * NODE + (kk));     \
    }

#define COMPUTE(A, B)                                                        \
    {                                                                        \
        s16x8 af0 = cvt8(A[0][0], A[0][1]);                                  \
        s16x8 af1 = cvt8(A[1][0], A[1][1]);                                  \
        _Pragma("unroll") for (int nt = 0; nt < 4; ++nt) {                   \
            s16x8 bf = __builtin_bit_cast(s16x8, B[nt]);                     \
            acc[0][nt] = __builtin_amdgcn_mfma_f32_16x16x32_bf16(            \
                af0, bf, acc[0][nt], 0, 0, 0);                               \
            acc[1][nt] = __builtin_amdgcn_mfma_f32_16x16x32_bf16(            \
                af1, bf, acc[1][nt], 0, 0, 0);                               \
        }                                                                    \
    }

    GLOAD(sa, sb, kbeg);
    for (int k = kbeg; k < kend; k += 64) {
        GLOAD(ta, tb, k + 32);
        COMPUTE(sa, sb);
        const int k2 = (k + 64 < kend) ? (k + 64) : kbeg;  // clamp: avoid OOB prefetch
        GLOAD(sa, sb, k2);
        COMPUTE(ta, tb);
    }
#undef GLOAD
#undef COMPUTE

    // ---- k-split reduction: ks=1 -> LDS, ks=0 adds + bias and stores ----
    if (ks == 1) {
#pragma unroll
        for (int mi = 0; mi < 2; ++mi)
#pragma unroll
            for (int nt = 0; nt < 4; ++nt)
#pragma unroll
                for (int r = 0; r < 4; ++r)
                    red[(nq * 32 + mi * 16 + quad * 4 + r) * 65 + nt * 16 + t16] =
                        acc[mi][nt][r];
    }
    __syncthreads();
    if (ks == 0) {
#pragma unroll
        for (int mi = 0; mi < 2; ++mi) {
            const int row = mi * 16 + quad * 4;
#pragma unroll
            for (int nt = 0; nt < 4; ++nt) {
                const float bv = bias2[nt * 16 + t16];
                float* op = out + ((size_t)nq * NODE + row0 + row) * OUTD + nt * 16 + t16;
#pragma unroll
                for (int r = 0; r < 4; ++r)
                    op[(size_t)r * OUTD] =
                        acc[mi][nt][r] +
                        red[(nq * 32 + row + r) * 65 + nt * 16 + t16] + bv;
            }
        }
    }
}

// ---------------------------------------------------------------------------
extern "C" void kernel_launch(void* const* d_in, const int* in_sizes, int n_in,
                              void* d_out, int out_size, void* d_ws, size_t ws_size,
                              hipStream_t stream) {
    const float* x     = (const float*)d_in[0];
    const float* adj   = (const float*)d_in[1];
    const float* nl_w  = (const float*)d_in[2];
    const float* nl_b  = (const float*)d_in[3];
    const float* w_out = (const float*)d_in[4];
    const float* b_out = (const float*)d_in[5];
    float* out = (float*)d_out;

    unsigned short* yt = (unsigned short*)d_ws;                       // 4 MB
    float* bias2 = (float*)((char*)d_ws + (size_t)NCOL * NODE * 2);   // 64 fp32

    bias2_kernel<<<1, 256, 0, stream>>>(nl_b, w_out, b_out, bias2);
    build_yt_kernel<<<512, 256, 0, stream>>>(x, nl_w, w_out, yt);
    gemm_adj_kernel<<<256, 512, 0, stream>>>(adj, yt, bias2, out);
}